// Round 7
// baseline (397.712 us; speedup 1.0000x reference)
//
#include <hip/hip_runtime.h>

// GCN: N=100000, E=800000, D=128, two GraphConv layers.
// R7: atomic-free CSR build. R4/R6 evidence: device-scope atomics execute
// memory-side (bypass L2) -> 1.6M random atomics = ~51MB of 32B HBM sector
// writes = ~80us floor. Replaced by LDS-histogram counting sort:
//   bighist: per (range,chunk) LDS histograms of col & row -> H, H2 (+x cast rides along)
//   reduceB: H,H2 -> dinv_in/dinv_out + scan1-style partial scan
//   scanB:   row_start + per-(chunk,node) cursor base
//   fillC:   LDS cursors assign unique slots; scattered 4B writes into 3.2MB srcs (L2-absorbed)

#define NN 100000
#define EE 800000
#define DD 128
#define NB1 98            // ceil(NN/1024) scan blocks
#define RC 16             // edge chunks
#define CHUNK 50000       // EE / RC
#define NR 8              // node ranges
#define RSZ 12500         // NN / NR  (LDS hist: 12500 uints = 50KB)
#define NTILE (NN / 16)   // 6250 MFMA row-tiles

typedef __attribute__((ext_vector_type(8))) short short8;
typedef __attribute__((ext_vector_type(4))) float floatx4;

__device__ inline float bf2f(unsigned int u16) {
    union { unsigned int i; float f; } c;
    c.i = u16 << 16;
    return c.f;
}
__device__ inline ushort f2bf(float f) {
    union { float f; unsigned int i; } c;
    c.f = f;
    unsigned int u = c.i;
    return (ushort)((u + 0x7fffu + ((u >> 16) & 1u)) >> 16);  // RNE
}

// ---------------- histograms (LDS) + x->bf16 cast, one launch ----------------
// blocks [0,128): col-hist -> H ; [128,256): row-hist -> H2 ; [256, 256+12500): cast
__global__ __launch_bounds__(256) void bighist_kernel(const int* __restrict__ row,
                                                      const int* __restrict__ col,
                                                      unsigned* __restrict__ H,
                                                      unsigned* __restrict__ H2,
                                                      const float* __restrict__ x,
                                                      ushort* __restrict__ xb) {
    __shared__ unsigned hist[RSZ];
    const int b = blockIdx.x;
    const int t = threadIdx.x;
    if (b < 2 * NR * RC) {
        const int hb = b & (NR * RC - 1);
        const int r = hb >> 4;            // node range
        const int c = hb & (RC - 1);      // edge chunk
        const int* key = (b < NR * RC) ? col : row;
        unsigned* Hd = (b < NR * RC) ? H : H2;
        const unsigned rbase = (unsigned)(r * RSZ);
        for (int i = t; i < RSZ; i += 256) hist[i] = 0u;
        __syncthreads();
        const int e0 = c * CHUNK;
        for (int i = t; i < CHUNK; i += 256) {
            unsigned u = (unsigned)key[e0 + i] - rbase;
            if (u < RSZ) atomicAdd(&hist[u], 1u);
        }
        __syncthreads();
        unsigned* dst = Hd + (size_t)c * NN + rbase;
        for (int i = t; i < RSZ; i += 256) dst[i] = hist[i];
    } else {
        int idx = (b - 2 * NR * RC) * 256 + t;   // one float4 per thread
        if (idx < NN * 32) {
            float4 v = ((const float4*)x)[idx];
            ushort4 o;
            o.x = f2bf(v.x); o.y = f2bf(v.y); o.z = f2bf(v.z); o.w = f2bf(v.w);
            ((ushort4*)xb)[idx] = o;
        }
    }
}

// ---------------- reduce H/H2 -> dinv arrays + scan1-style partial scan ----------------
__global__ __launch_bounds__(256) void reduceB_kernel(const unsigned* __restrict__ H,
                                                      const unsigned* __restrict__ H2,
                                                      int* __restrict__ excl,
                                                      int* __restrict__ bsums,
                                                      float* __restrict__ dinv_out,
                                                      float* __restrict__ dinv_in) {
    __shared__ int tmp[256];
    const int t = threadIdx.x;
    const int base = blockIdx.x * 1024 + t * 4;
    int a[4] = {0, 0, 0, 0};
    int o[4] = {0, 0, 0, 0};
    for (int c = 0; c < RC; ++c) {
        const unsigned* hc  = H  + (size_t)c * NN;
        const unsigned* h2c = H2 + (size_t)c * NN;
#pragma unroll
        for (int q = 0; q < 4; ++q) {
            if (base + q < NN) {
                a[q] += (int)hc[base + q];
                o[q] += (int)h2c[base + q];
            }
        }
    }
#pragma unroll
    for (int q = 0; q < 4; ++q) {
        if (base + q < NN) {
            dinv_in[base + q]  = rsqrtf((float)max(a[q], 1));
            dinv_out[base + q] = rsqrtf((float)max(o[q], 1));
        }
    }
    int s = a[0] + a[1] + a[2] + a[3];
    tmp[t] = s;
    __syncthreads();
    for (int off = 1; off < 256; off <<= 1) {
        int v = 0;
        if (t >= off) v = tmp[t - off];
        __syncthreads();
        tmp[t] += v;
        __syncthreads();
    }
    int excl_s = tmp[t] - s;
    if (t == 255) bsums[blockIdx.x] = tmp[t];
    int run = excl_s;
#pragma unroll
    for (int q = 0; q < 4; ++q) {
        if (base + q < NN) excl[base + q] = run;
        run += a[q];
    }
}

// ---------------- scan level 2 + row_start + per-chunk cursor base ----------------
__global__ __launch_bounds__(256) void scanB_kernel(const int* __restrict__ excl,
                                                    const int* __restrict__ bsums,
                                                    const unsigned* __restrict__ H,
                                                    int* __restrict__ row_start,
                                                    int* __restrict__ base) {
    __shared__ int tmp[128];
    const int t = threadIdx.x;
    if (t < 128) tmp[t] = (t < NB1) ? bsums[t] : 0;
    __syncthreads();
    for (int off = 1; off < 128; off <<= 1) {
        int v = 0;
        if (t < 128 && t >= off) v = tmp[t - off];
        __syncthreads();
        if (t < 128) tmp[t] += v;
        __syncthreads();
    }
    const int pfx = (blockIdx.x == 0) ? 0 : tmp[blockIdx.x - 1];  // exclusive prefix
    const int i0 = blockIdx.x * 1024 + t * 4;
#pragma unroll
    for (int q = 0; q < 4; ++q) {
        int i = i0 + q;
        if (i < NN) {
            int rs = excl[i] + pfx;
            row_start[i] = rs;
            int run = rs;
            for (int c = 0; c < RC; ++c) {
                size_t idx = (size_t)c * NN + i;
                base[idx] = run;
                run += (int)H[idx];
            }
        }
    }
    if (blockIdx.x == 0 && t == 0) row_start[NN] = EE;
}

// ---------------- CSR fill: LDS cursors, no global atomics ----------------
__global__ __launch_bounds__(256) void fillC_kernel(const int* __restrict__ row,
                                                    const int* __restrict__ col,
                                                    const int* __restrict__ base,
                                                    int* __restrict__ srcs) {
    __shared__ unsigned cur[RSZ];
    const int r = blockIdx.x >> 4;
    const int c = blockIdx.x & (RC - 1);
    const unsigned rbase = (unsigned)(r * RSZ);
    const int* bc = base + (size_t)c * NN + rbase;
    for (int i = threadIdx.x; i < RSZ; i += 256) cur[i] = (unsigned)bc[i];
    __syncthreads();
    const int e0 = c * CHUNK;
    for (int i = threadIdx.x; i < CHUNK; i += 256) {
        int e = e0 + i;
        unsigned u = (unsigned)col[e] - rbase;
        int rv = row[e];
        if (u < RSZ) {
            unsigned slot = atomicAdd(&cur[u], 1u);
            srcs[slot] = rv;
        }
    }
}

// ---------------- gather: 16 lanes/node, uint4/lane, 4-edge unroll ----------------
__global__ __launch_bounds__(256) void gather_kernel(const ushort* __restrict__ src,
                                                     const int* __restrict__ row_start,
                                                     const int* __restrict__ srcs,
                                                     const float* __restrict__ dinv_out,
                                                     ushort* __restrict__ agg) {
    const int node = blockIdx.x * 16 + (threadIdx.x >> 4);
    const int lane = threadIdx.x & 15;
    if (node >= NN) return;
    int p = row_start[node];
    const int end = row_start[node + 1];
    float a0 = 0.f, a1 = 0.f, a2 = 0.f, a3 = 0.f;
    float a4 = 0.f, a5 = 0.f, a6 = 0.f, a7 = 0.f;

#define ACCUM(V, C)                                  \
    do {                                             \
        a0 += bf2f((V).x & 0xffffu) * (C);           \
        a1 += bf2f((V).x >> 16) * (C);               \
        a2 += bf2f((V).y & 0xffffu) * (C);           \
        a3 += bf2f((V).y >> 16) * (C);               \
        a4 += bf2f((V).z & 0xffffu) * (C);           \
        a5 += bf2f((V).z >> 16) * (C);               \
        a6 += bf2f((V).w & 0xffffu) * (C);           \
        a7 += bf2f((V).w >> 16) * (C);               \
    } while (0)

    for (; p + 3 < end; p += 4) {
        int s0 = srcs[p];
        int s1 = srcs[p + 1];
        int s2 = srcs[p + 2];
        int s3 = srcs[p + 3];
        float c0 = dinv_out[s0];
        float c1 = dinv_out[s1];
        float c2 = dinv_out[s2];
        float c3 = dinv_out[s3];
        uint4 v0 = ((const uint4*)(src + (size_t)s0 * DD))[lane];
        uint4 v1 = ((const uint4*)(src + (size_t)s1 * DD))[lane];
        uint4 v2 = ((const uint4*)(src + (size_t)s2 * DD))[lane];
        uint4 v3 = ((const uint4*)(src + (size_t)s3 * DD))[lane];
        ACCUM(v0, c0); ACCUM(v1, c1); ACCUM(v2, c2); ACCUM(v3, c3);
    }
    for (; p < end; ++p) {
        int s0 = srcs[p];
        float c0 = dinv_out[s0];
        uint4 v0 = ((const uint4*)(src + (size_t)s0 * DD))[lane];
        ACCUM(v0, c0);
    }
#undef ACCUM

    uint4 o;
    o.x = (unsigned int)f2bf(a0) | ((unsigned int)f2bf(a1) << 16);
    o.y = (unsigned int)f2bf(a2) | ((unsigned int)f2bf(a3) << 16);
    o.z = (unsigned int)f2bf(a4) | ((unsigned int)f2bf(a5) << 16);
    o.w = (unsigned int)f2bf(a6) | ((unsigned int)f2bf(a7) << 16);
    ((uint4*)(agg + (size_t)node * DD))[lane] = o;
}

// ---------------- MFMA bf16 GEMM + epilogue ----------------
template <bool L1>
__global__ __launch_bounds__(256) void gemm_ep(const ushort* __restrict__ agg,
                                               const float* __restrict__ W,
                                               const float* __restrict__ bias,
                                               const float* __restrict__ dinv_in,
                                               const float* __restrict__ x,
                                               ushort* __restrict__ hb,
                                               float* __restrict__ out) {
    __shared__ ushort Ws[128 * 136];
    {   // stage W (fp32 -> bf16) into LDS
        int j = threadIdx.x >> 1;
        int k0 = (threadIdx.x & 1) * 64;
        const float4* wp = (const float4*)(W + (size_t)j * DD + k0);
        ushort* dst = Ws + j * 136 + k0;
#pragma unroll
        for (int q = 0; q < 16; ++q) {
            float4 v = wp[q];
            ushort4 o;
            o.x = f2bf(v.x); o.y = f2bf(v.y); o.z = f2bf(v.z); o.w = f2bf(v.w);
            *(ushort4*)(dst + q * 4) = o;
        }
    }
    __syncthreads();

    const int wave = threadIdx.x >> 6;
    const int lane = threadIdx.x & 63;
    const int tile = blockIdx.x * 4 + wave;
    if (tile >= NTILE) return;
    const int mi = lane & 15;
    const int quad = lane >> 4;
    const int m0 = tile * 16;

    floatx4 acc[8];
#pragma unroll
    for (int t = 0; t < 8; ++t) acc[t] = (floatx4){0.f, 0.f, 0.f, 0.f};

    const ushort* ap = agg + (size_t)(m0 + mi) * DD + quad * 8;
#pragma unroll
    for (int s = 0; s < 4; ++s) {
        short8 a = *(const short8*)(ap + s * 32);
#pragma unroll
        for (int t = 0; t < 8; ++t) {
            short8 b = *(const short8*)(Ws + (t * 16 + mi) * 136 + s * 32 + quad * 8);
            acc[t] = __builtin_amdgcn_mfma_f32_16x16x32_bf16(a, b, acc[t], 0, 0, 0);
        }
    }

    // C/D layout: col = lane&15, row = quad*4 + reg
    float dv[4];
#pragma unroll
    for (int i = 0; i < 4; ++i) dv[i] = dinv_in[m0 + quad * 4 + i];
#pragma unroll
    for (int t = 0; t < 8; ++t) {
        int c = t * 16 + mi;
        float bv = bias[c];
#pragma unroll
        for (int i = 0; i < 4; ++i) {
            int r = m0 + quad * 4 + i;
            float o = (acc[t][i] + bv) * dv[i];
            if (L1) {
                o += x[(size_t)r * DD + c];
                o = fmaxf(o, 0.f);
                hb[(size_t)r * DD + c] = f2bf(o);
            } else {
                out[(size_t)r * DD + c] = o;
            }
        }
    }
}

extern "C" void kernel_launch(void* const* d_in, const int* in_sizes, int n_in,
                              void* d_out, int out_size, void* d_ws, size_t ws_size,
                              hipStream_t stream) {
    const float* x  = (const float*)d_in[0];
    const int*   ei = (const int*)d_in[1];
    const float* W1 = (const float*)d_in[2];
    const float* b1 = (const float*)d_in[3];
    const float* W2 = (const float*)d_in[4];
    const float* b2 = (const float*)d_in[5];
    float* out = (float*)d_out;

    const int* row = ei;        // edge_index[0] (source)
    const int* col = ei + EE;   // edge_index[1] (target)

    // workspace. agg region (25.6 MB) also hosts H (6.4) + H2/base (6.4):
    //   H dead after scanB; H2 dead after reduceB (base overlays it, written
    //   in scanB); base dead after fillC; agg first written by gather1.
    // hb aliases xb (xb dead after gather1; hb written by gemm1).
    ushort* xb      = (ushort*)d_ws;                 // N*DD bf16 (25.6 MB)
    ushort* agg     = xb + (size_t)NN * DD;          // N*DD bf16 (25.6 MB)
    unsigned* H     = (unsigned*)agg;                // RC*NN uints (6.4 MB)
    unsigned* H2    = H + (size_t)RC * NN;           // RC*NN uints (6.4 MB)
    int*    basec   = (int*)H2;                      // overlays H2
    ushort* hb      = xb;                            // aliased
    float* dinv_out = (float*)(agg + (size_t)NN * DD);
    float* dinv_in  = dinv_out + NN;
    int*   excl     = (int*)(dinv_in + NN);          // N
    int*   row_st   = excl + NN;                     // N+1
    int*   srcs     = row_st + NN + 1;               // E
    int*   bsums    = srcs + EE;                     // 128

    // ---- CSR build (no global atomics) + x cast ----
    bighist_kernel<<<2 * NR * RC + (NN * 32 + 255) / 256, 256, 0, stream>>>(
        row, col, H, H2, x, xb);
    reduceB_kernel<<<NB1, 256, 0, stream>>>(H, H2, excl, bsums, dinv_out, dinv_in);
    scanB_kernel<<<NB1, 256, 0, stream>>>(excl, bsums, H, row_st, basec);
    fillC_kernel<<<NR * RC, 256, 0, stream>>>(row, col, basec, srcs);

    // ---- layer 1 ----
    gather_kernel<<<(NN + 15) / 16, 256, 0, stream>>>(xb, row_st, srcs, dinv_out, agg);
    gemm_ep<true><<<(NTILE + 3) / 4, 256, 0, stream>>>(agg, W1, b1, dinv_in, x, hb, nullptr);

    // ---- layer 2 ----
    gather_kernel<<<(NN + 15) / 16, 256, 0, stream>>>(hb, row_st, srcs, dinv_out, agg);
    gemm_ep<false><<<(NTILE + 3) / 4, 256, 0, stream>>>(agg, W2, b2, dinv_in, nullptr, nullptr, out);
}